// Round 17
// baseline (80.681 us; speedup 1.0000x reference)
//
#include <hip/hip_runtime.h>
#include <hip/hip_bf16.h>

typedef __attribute__((ext_vector_type(4))) float f32x4;
typedef __attribute__((ext_vector_type(8))) short s16x8;
typedef __attribute__((ext_vector_type(8))) unsigned short u16x8;
typedef __attribute__((ext_vector_type(4))) unsigned int u32x4;

#define DEVFN static __device__ __forceinline__

DEVFN unsigned short f2bf(float f) {
  union { float f; unsigned int u; } v; v.f = f;
  unsigned int u = v.u;
  u += 0x7fffu + ((u >> 16) & 1u);   // RNE
  return (unsigned short)(u >> 16);
}

DEVFN unsigned int cvt_pk(float a, float b) {
  __hip_bfloat162 h = __float22bfloat162_rn(make_float2(a, b));
  union { __hip_bfloat162 h; unsigned int u; } v; v.h = h; return v.u;
}

DEVFN void gl_lds16(const void* g, void* l) {
  __builtin_amdgcn_global_load_lds((__attribute__((address_space(1))) void*)g,
                                   (__attribute__((address_space(3))) void*)l, 16, 0, 0);
}

#define SB() __builtin_amdgcn_sched_barrier(0)
#define VMW(n) asm volatile("s_waitcnt vmcnt(" #n ")" ::: "memory")
#define LGKM0() asm volatile("s_waitcnt lgkmcnt(0)" ::: "memory")
#define BAR() { SB(); __builtin_amdgcn_s_barrier(); SB(); }

// ws layout (bytes)
#define DG_OFF 0
#define DB_OFF 2048
#define UG_OFF 4096
#define UB_OFF 12288
#define W1_BYTE 81920        // [32 ks][256 n][32 k] bf16, 64B rows, g^=((n>>1)&3)  (512 KB)
#define W2_BYTE 606208       // [8 nt][4 kc][128 n][64 k] bf16, g^=(n&7)            (512 KB)

// ---------- prep: W1 (0..31) + W2 (32..63) + coef (64..223) ----------
__global__ void prep_kernel(const float* __restrict__ cond,
                            const float* __restrict__ dgm, const float* __restrict__ dbt,
                            const float* __restrict__ ugm, const float* __restrict__ ubt,
                            const float* __restrict__ Wd, const float* __restrict__ Wu,
                            char* __restrict__ ws) {
  __shared__ float lc[4096];
  __shared__ float red[2048];
  const int t = threadIdx.x;

  if (blockIdx.x < 32) {
    const int ks = blockIdx.x;
    const int n = t;
    const float* sp = Wd + (size_t)(ks * 32) * 256 + n;
    unsigned short tmp[32];
#pragma unroll
    for (int kk = 0; kk < 32; ++kk) tmp[kk] = f2bf(sp[(size_t)kk * 256]);
    char* dst = ws + W1_BYTE + (size_t)ks * 16384 + n * 64;
#pragma unroll
    for (int g = 0; g < 4; ++g) {
      u16x8 v;
#pragma unroll
      for (int e = 0; e < 8; ++e) v[e] = tmp[g * 8 + e];
      *(u16x8*)(dst + ((g ^ ((n >> 1) & 3)) << 4)) = v;
    }
    return;
  }
  if (blockIdx.x < 64) {
    int b2 = blockIdx.x - 32;
    int ntile = b2 >> 2, kc = b2 & 3;
    const int n = t >> 1, kh = t & 1;
    const float* sp = Wu + (size_t)(kc * 64 + kh * 32) * 1024 + ntile * 128 + n;
    unsigned short tmp[32];
#pragma unroll
    for (int kk = 0; kk < 32; ++kk) tmp[kk] = f2bf(sp[(size_t)kk * 1024]);
    char* dst = ws + W2_BYTE + (size_t)(ntile * 4 + kc) * 16384 + n * 128;
#pragma unroll
    for (int gi = 0; gi < 4; ++gi) {
      u16x8 v;
#pragma unroll
      for (int e = 0; e < 8; ++e) v[e] = tmp[gi * 8 + e];
      int g = kh * 4 + gi;
      *(u16x8*)(dst + ((g ^ (n & 7)) << 4)) = v;
    }
    return;
  }

  float* coef = (float*)ws;
#pragma unroll
  for (int i = 0; i < 16; ++i) lc[t + i * 256] = cond[t + i * 256];
  __syncthreads();
  const int bid2 = blockIdx.x - 64;
  const int col = bid2 * 16 + (t & 15);
  const int ks = t >> 4;
  const float* src; int ncol, cl;
  if (col < 256)       { src = dgm; ncol = 256;  cl = col; }
  else if (col < 512)  { src = dbt; ncol = 256;  cl = col - 256; }
  else if (col < 1536) { src = ugm; ncol = 1024; cl = col - 512; }
  else                 { src = ubt; ncol = 1024; cl = col - 1536; }
  float acc[8] = {};
  for (int k = ks * 32; k < ks * 32 + 32; ++k) {
    float g = src[(size_t)k * ncol + cl];
#pragma unroll
    for (int b = 0; b < 8; ++b) acc[b] = fmaf(lc[b * 512 + k], g, acc[b]);
  }
#pragma unroll
  for (int b = 0; b < 8; ++b) red[(ks * 16 + (t & 15)) * 8 + b] = acc[b];
  __syncthreads();
  if (t < 128) {
    int c = t >> 3, b = t & 7;
    float s = 0.f;
#pragma unroll
    for (int k2 = 0; k2 < 16; ++k2) s += red[(k2 * 16 + c) * 8 + b];
    int colg = bid2 * 16 + c;
    float* dst; int ncol2, cl2;
    if (colg < 256)       { dst = coef + DG_OFF; ncol2 = 256;  cl2 = colg; }
    else if (colg < 512)  { dst = coef + DB_OFF; ncol2 = 256;  cl2 = colg - 256; }
    else if (colg < 1536) { dst = coef + UG_OFF; ncol2 = 1024; cl2 = colg - 512; }
    else                  { dst = coef + UB_OFF; ncol2 = 1024; cl2 = colg - 1536; }
    dst[b * ncol2 + cl2] = s;
  }
}

// ---------- fused kernel: BM=64, 512 blocks x 512 threads, 2 blocks/CU ----------
// LDS 80 KiB: X f32 quad-buf @0 (4x8K, aliases act) | W1/W2 triple-buffer @32K (3x16K)
// Phase 1: BK=32, X 4-deep prefetch (3-step cover), W1 3-buf, uniform VMW(4).
// Phase 2: verbatim r15.
__global__ __launch_bounds__(512, 4)
void fused_kernel(const float* __restrict__ X, char* __restrict__ ws,
                  float* __restrict__ out) {
  __shared__ char lds[81920];
  const int tid = threadIdx.x;
  const int lane = tid & 63, lr = lane & 15, lq = lane >> 4;
  const int wave = tid >> 6;
  const int wm1 = wave >> 1, wn1 = wave & 1;   // phase 1: 4m x 2n
  const int wm = wave >> 2, wn = wave & 3;     // phase 2: 2m x 4n

  const int raw = blockIdx.x;
  const int m = (raw & 7) * 64 + (raw >> 3);   // XCD-chunked, 512 % 8 == 0
  const int row0 = m << 6;
  const int b = m >> 6;

  const float* coef = (const float*)ws;
  const char* w1 = ws + W1_BYTE;
  const char* w2 = ws + W2_BYTE;

  // ===== phase 1: X @ Wd, 32 sub-steps of K=32, 1 barrier each =====
  // X tile u: [64 r][32 k] f32, 8 KB, buffer u&3. Row 128 B = 8 granules,
  // swizzle g^(r&7). Thread (srow=tid>>3, sg=tid&7) stages source granule
  // sg^(srow&7) into linear dest (rule #21 both-sides).
  const int srow = tid >> 3, sg = tid & 7;
  const float* xsrc = X + (size_t)(row0 + srow) * 1024 + ((sg ^ (srow & 7)) << 2);

  int aoff1[2];
  {
    int r = wm1 * 16 + lr;
    aoff1[0] = r * 128 + (((lq * 2) ^ (r & 7)) << 4);
    aoff1[1] = r * 128 + (((lq * 2 + 1) ^ (r & 7)) << 4);
  }
  int boff[8];
#pragma unroll
  for (int nf = 0; nf < 8; ++nf) {
    int n = wn1 * 128 + nf * 16 + lr;
    boff[nf] = n * 64 + ((lq ^ ((n >> 1) & 3)) << 4);
  }

  f32x4 acc1[8] = {};
  float hacc = 0.f;

#define STAGE_X(u)                                                               \
  gl_lds16(xsrc + (size_t)(u) * 32, lds + ((u) & 3) * 8192 + tid * 16);
#define STAGE_W1(ks)                                                             \
  { char* dst = lds + 32768 + ((ks) % 3) * 16384;                                \
    gl_lds16(w1 + (size_t)(ks) * 16384 + tid * 16, dst + tid * 16);              \
    gl_lds16(w1 + (size_t)(ks) * 16384 + 8192 + tid * 16, dst + 8192 + tid * 16); }

  // prologue: W1(0),X(0),W1(1),X(1),X(2) in flight; retire W1(0)+X(0)
  STAGE_W1(0); STAGE_X(0); STAGE_W1(1); STAGE_X(1); STAGE_X(2);
  VMW(4); BAR();

#pragma unroll
  for (int s = 0; s < 32; ++s) {
    // ---- issue stage (before compute) ----
    if (s + 2 < 32) STAGE_W1(s + 2);
    if (s + 3 < 32) STAGE_X(s + 3);
    // ---- compute sub-step: X buf s&3, W1 buf s%3 ----
    {
      const char* Xc = lds + (s & 3) * 8192;
      const char* Wb = lds + 32768 + (s % 3) * 16384;
      f32x4 fa0 = *(const f32x4*)(Xc + aoff1[0]);
      f32x4 fa1 = *(const f32x4*)(Xc + aoff1[1]);
      if (wn1 == 0)
        hacc += fa0[0] + fa0[1] + fa0[2] + fa0[3] +
                fa1[0] + fa1[1] + fa1[2] + fa1[3];
      union { u32x4 u; s16x8 s_; } cv;
      cv.u[0] = cvt_pk(fa0[0], fa0[1]); cv.u[1] = cvt_pk(fa0[2], fa0[3]);
      cv.u[2] = cvt_pk(fa1[0], fa1[1]); cv.u[3] = cvt_pk(fa1[2], fa1[3]);
      s16x8 afr = cv.s_;
      s16x8 bfr[8];
#pragma unroll
      for (int nf = 0; nf < 8; ++nf) bfr[nf] = *(const s16x8*)(Wb + boff[nf]);
#pragma unroll
      for (int nf = 0; nf < 8; ++nf)
        acc1[nf] = __builtin_amdgcn_mfma_f32_16x16x32_bf16(afr, bfr[nf],
                                                           acc1[nf], 0, 0, 0);
    }
    LGKM0(); SB();
    // ---- counted trailing wait: retire W1(s+1) (and older X(s+1)) ----
    if (s <= 28)      { VMW(4); }   // leave X(s+2), W1(s+2), X(s+3)
    else if (s == 29) { VMW(3); }   // leave X(31), W1(31)
    else if (s == 30) { VMW(0); }   // all retired
    BAR();
  }

  // ===== phase-1 epilogue: hsum, modulate+relu -> act LDS, asum =====
  float* hsumb = (float*)(lds + 32768);          // 64 f32 (W1 region dead)
  float* asp   = (float*)(lds + 33024);          // [2 wn1][64 r] f32
  if (wn1 == 0) {
    float s = hacc;
    s += __shfl_xor(s, 16); s += __shfl_xor(s, 32);
    if (lq == 0) hsumb[wm1 * 16 + lr] = s;
  }
  __syncthreads();

  float dgv[8], dbv[8];
#pragma unroll
  for (int nf = 0; nf < 8; ++nf) {
    int h = wn1 * 128 + nf * 16 + lr;
    dgv[nf] = coef[DG_OFF + b * 256 + h];
    dbv[nf] = coef[DB_OFF + b * 256 + h];
  }

  float asacc[4] = {};
#pragma unroll
  for (int nf = 0; nf < 8; ++nf) {
    int hh = wn1 * 128 + nf * 16 + lr;
    int kc = hh >> 6, kl = hh & 63;
    int g = kl >> 3;
    char* nbase = lds + kc * 8192 + (kl & 7) * 2;
    float dg_ = dgv[nf], db_ = dbv[nf];
#pragma unroll
    for (int j = 0; j < 4; ++j) {
      int r = wm1 * 16 + lq * 4 + j;
      float v = acc1[nf][j] * dg_ + db_ * hsumb[r];
      v = fmaxf(v, 0.f);
      asacc[j] += v;
      *(unsigned short*)(nbase + r * 128 + ((g ^ (r & 7)) << 4)) = f2bf(v);
    }
  }
#pragma unroll
  for (int j = 0; j < 4; ++j) {
    float s = asacc[j];
    s += __shfl_xor(s, 1); s += __shfl_xor(s, 2); s += __shfl_xor(s, 4); s += __shfl_xor(s, 8);
    if (lr == 0) asp[wn1 * 64 + wm1 * 16 + lq * 4 + j] = s;
  }
  __syncthreads();

  float asv[2][4];
#pragma unroll
  for (int mf = 0; mf < 2; ++mf)
#pragma unroll
    for (int j = 0; j < 4; ++j) {
      int r = wm * 32 + mf * 16 + lq * 4 + j;
      asv[mf][j] = asp[r] + asp[64 + r];
    }
  // preload all per-nt phase-2 modulation coefs (no in-loop coef loads)
  float ugA[8], ubA[8];
#pragma unroll
  for (int nt = 0; nt < 8; ++nt) {
    int d = nt * 128 + wn * 32 + lr;
    ugA[nt] = coef[UG_OFF + b * 1024 + d];
    ubA[nt] = coef[UB_OFF + b * 1024 + d];
  }
  float ugB[8], ubB[8];
#pragma unroll
  for (int nt = 0; nt < 8; ++nt) {
    int d = nt * 128 + wn * 32 + 16 + lr;
    ugB[nt] = coef[UG_OFF + b * 1024 + d];
    ubB[nt] = coef[UB_OFF + b * 1024 + d];
  }
  __syncthreads();   // asp consumed before W2 staging overwrites 32768..

  // ===== phase 2: act @ Wu, 32 steps (8 nt x 4 kc) — verbatim r15 =====
  int a2off[2][2], b2off[2][2];
#pragma unroll
  for (int mf = 0; mf < 2; ++mf)
#pragma unroll
    for (int kf = 0; kf < 2; ++kf) {
      int r = wm * 32 + mf * 16 + lr;
      a2off[mf][kf] = r * 128 + (((kf * 4 + lq) ^ (r & 7)) << 4);
    }
#pragma unroll
  for (int nf = 0; nf < 2; ++nf)
#pragma unroll
    for (int kf = 0; kf < 2; ++kf) {
      int nl = wn * 32 + nf * 16 + lr;
      b2off[nf][kf] = nl * 128 + (((kf * 4 + lq) ^ (nl & 7)) << 4);
    }

#define W2B(s) (lds + 32768 + ((s) % 3) * 16384)
#define STAGE_W2(s)                                                              \
  { gl_lds16(w2 + (size_t)(s) * 16384 + tid * 16, W2B(s) + tid * 16);            \
    gl_lds16(w2 + (size_t)(s) * 16384 + 8192 + tid * 16,                         \
             W2B(s) + 8192 + tid * 16); }

  STAGE_W2(0); STAGE_W2(1);
  VMW(2); BAR();

#pragma unroll
  for (int s = 0; s < 32; ++s) {
    const int nt = s >> 2, kc = s & 3;
    f32x4 acc2[2][2];
    if (kc == 0) {
#pragma unroll
      for (int mf = 0; mf < 2; ++mf)
#pragma unroll
        for (int nf = 0; nf < 2; ++nf) acc2[mf][nf] = (f32x4){0.f, 0.f, 0.f, 0.f};
    }
    const char* Wb = W2B(s);
#pragma unroll
    for (int kf = 0; kf < 2; ++kf) {
      s16x8 a2[2], bb[2];
#pragma unroll
      for (int mf = 0; mf < 2; ++mf)
        a2[mf] = *(const s16x8*)(lds + kc * 8192 + a2off[mf][kf]);
#pragma unroll
      for (int nf = 0; nf < 2; ++nf)
        bb[nf] = *(const s16x8*)(Wb + b2off[nf][kf]);
#pragma unroll
      for (int mf = 0; mf < 2; ++mf)
#pragma unroll
        for (int nf = 0; nf < 2; ++nf)
          acc2[mf][nf] = __builtin_amdgcn_mfma_f32_16x16x32_bf16(a2[mf], bb[nf], acc2[mf][nf], 0, 0, 0);
    }
    LGKM0(); SB();

    if (s + 2 < 32) STAGE_W2(s + 2);
    if (kc == 3) {
#pragma unroll
      for (int mf = 0; mf < 2; ++mf)
#pragma unroll
        for (int j = 0; j < 4; ++j) {
          int r = wm * 32 + mf * 16 + lq * 4 + j;
          size_t gbase = (size_t)(row0 + r) * 1024 + nt * 128 + wn * 32;
          size_t gi0 = gbase + lr;
          size_t gi1 = gbase + 16 + lr;
          out[gi0] = acc2[mf][0][j] * ugA[nt] + ubA[nt] * asv[mf][j] + X[gi0];
          out[gi1] = acc2[mf][1][j] * ugB[nt] + ubB[nt] * asv[mf][j] + X[gi1];
        }
    }
    if (s < 31) {
      if (s + 2 >= 32)  { VMW(0); }
      else if (kc == 3) { VMW(16); }
      else              { VMW(2); }
      BAR();
    }
  }
}

extern "C" void kernel_launch(void* const* d_in, const int* in_sizes, int n_in,
                              void* d_out, int out_size, void* d_ws, size_t ws_size,
                              hipStream_t stream) {
  const float* hidden       = (const float*)d_in[0];
  const float* conditions   = (const float*)d_in[1];
  const float* down_project = (const float*)d_in[2];
  const float* down_gamma   = (const float*)d_in[3];
  const float* down_beta    = (const float*)d_in[4];
  const float* up_project   = (const float*)d_in[5];
  const float* up_gamma     = (const float*)d_in[6];
  const float* up_beta      = (const float*)d_in[7];
  float* out = (float*)d_out;
  char* ws = (char*)d_ws;

  prep_kernel<<<224, 256, 0, stream>>>(conditions, down_gamma, down_beta, up_gamma, up_beta,
                                       down_project, up_project, ws);
  fused_kernel<<<512, 512, 0, stream>>>(hidden, ws, out);
}

// Round 18
// 79.105 us; speedup vs baseline: 1.0199x; 1.0199x over previous
//
#include <hip/hip_runtime.h>
#include <hip/hip_bf16.h>

typedef __attribute__((ext_vector_type(4))) float f32x4;
typedef __attribute__((ext_vector_type(8))) short s16x8;
typedef __attribute__((ext_vector_type(8))) unsigned short u16x8;
typedef __attribute__((ext_vector_type(4))) unsigned int u32x4;

#define DEVFN static __device__ __forceinline__

DEVFN unsigned short f2bf(float f) {
  union { float f; unsigned int u; } v; v.f = f;
  unsigned int u = v.u;
  u += 0x7fffu + ((u >> 16) & 1u);   // RNE
  return (unsigned short)(u >> 16);
}

DEVFN unsigned int cvt_pk(float a, float b) {
  __hip_bfloat162 h = __float22bfloat162_rn(make_float2(a, b));
  union { __hip_bfloat162 h; unsigned int u; } v; v.h = h; return v.u;
}

DEVFN void gl_lds16(const void* g, void* l) {
  __builtin_amdgcn_global_load_lds((__attribute__((address_space(1))) void*)g,
                                   (__attribute__((address_space(3))) void*)l, 16, 0, 0);
}

#define SB() __builtin_amdgcn_sched_barrier(0)
#define VMW(n) asm volatile("s_waitcnt vmcnt(" #n ")" ::: "memory")
#define LGKM0() asm volatile("s_waitcnt lgkmcnt(0)" ::: "memory")
#define BAR() { SB(); __builtin_amdgcn_s_barrier(); SB(); }
#define PRIO_HI() __builtin_amdgcn_s_setprio(1)
#define PRIO_LO() __builtin_amdgcn_s_setprio(0)

// ws layout (bytes)
#define DG_OFF 0
#define DB_OFF 2048
#define UG_OFF 4096
#define UB_OFF 12288
#define W1_BYTE 81920        // [32 ks][256 n][32 k] bf16, 64B rows, g^=((n>>1)&3)  (512 KB)
#define W2_BYTE 606208       // [8 nt][4 kc][128 n][64 k] bf16, g^=(n&7)            (512 KB)

// ---------- prep: W1 (0..31) + W2 (32..63) + coef (64..223) ----------
__global__ void prep_kernel(const float* __restrict__ cond,
                            const float* __restrict__ dgm, const float* __restrict__ dbt,
                            const float* __restrict__ ugm, const float* __restrict__ ubt,
                            const float* __restrict__ Wd, const float* __restrict__ Wu,
                            char* __restrict__ ws) {
  __shared__ float lc[4096];
  __shared__ float red[2048];
  const int t = threadIdx.x;

  if (blockIdx.x < 32) {
    const int ks = blockIdx.x;
    const int n = t;
    const float* sp = Wd + (size_t)(ks * 32) * 256 + n;
    unsigned short tmp[32];
#pragma unroll
    for (int kk = 0; kk < 32; ++kk) tmp[kk] = f2bf(sp[(size_t)kk * 256]);
    char* dst = ws + W1_BYTE + (size_t)ks * 16384 + n * 64;
#pragma unroll
    for (int g = 0; g < 4; ++g) {
      u16x8 v;
#pragma unroll
      for (int e = 0; e < 8; ++e) v[e] = tmp[g * 8 + e];
      *(u16x8*)(dst + ((g ^ ((n >> 1) & 3)) << 4)) = v;
    }
    return;
  }
  if (blockIdx.x < 64) {
    int b2 = blockIdx.x - 32;
    int ntile = b2 >> 2, kc = b2 & 3;
    const int n = t >> 1, kh = t & 1;
    const float* sp = Wu + (size_t)(kc * 64 + kh * 32) * 1024 + ntile * 128 + n;
    unsigned short tmp[32];
#pragma unroll
    for (int kk = 0; kk < 32; ++kk) tmp[kk] = f2bf(sp[(size_t)kk * 1024]);
    char* dst = ws + W2_BYTE + (size_t)(ntile * 4 + kc) * 16384 + n * 128;
#pragma unroll
    for (int gi = 0; gi < 4; ++gi) {
      u16x8 v;
#pragma unroll
      for (int e = 0; e < 8; ++e) v[e] = tmp[gi * 8 + e];
      int g = kh * 4 + gi;
      *(u16x8*)(dst + ((g ^ (n & 7)) << 4)) = v;
    }
    return;
  }

  float* coef = (float*)ws;
#pragma unroll
  for (int i = 0; i < 16; ++i) lc[t + i * 256] = cond[t + i * 256];
  __syncthreads();
  const int bid2 = blockIdx.x - 64;
  const int col = bid2 * 16 + (t & 15);
  const int ks = t >> 4;
  const float* src; int ncol, cl;
  if (col < 256)       { src = dgm; ncol = 256;  cl = col; }
  else if (col < 512)  { src = dbt; ncol = 256;  cl = col - 256; }
  else if (col < 1536) { src = ugm; ncol = 1024; cl = col - 512; }
  else                 { src = ubt; ncol = 1024; cl = col - 1536; }
  float acc[8] = {};
  for (int k = ks * 32; k < ks * 32 + 32; ++k) {
    float g = src[(size_t)k * ncol + cl];
#pragma unroll
    for (int b = 0; b < 8; ++b) acc[b] = fmaf(lc[b * 512 + k], g, acc[b]);
  }
#pragma unroll
  for (int b = 0; b < 8; ++b) red[(ks * 16 + (t & 15)) * 8 + b] = acc[b];
  __syncthreads();
  if (t < 128) {
    int c = t >> 3, b = t & 7;
    float s = 0.f;
#pragma unroll
    for (int k2 = 0; k2 < 16; ++k2) s += red[(k2 * 16 + c) * 8 + b];
    int colg = bid2 * 16 + c;
    float* dst; int ncol2, cl2;
    if (colg < 256)       { dst = coef + DG_OFF; ncol2 = 256;  cl2 = colg; }
    else if (colg < 512)  { dst = coef + DB_OFF; ncol2 = 256;  cl2 = colg - 256; }
    else if (colg < 1536) { dst = coef + UG_OFF; ncol2 = 1024; cl2 = colg - 512; }
    else                  { dst = coef + UB_OFF; ncol2 = 1024; cl2 = colg - 1536; }
    dst[b * ncol2 + cl2] = s;
  }
}

// ---------- fused kernel: BM=64, 512 blocks x 512 threads, 2 blocks/CU ----------
// r15 base (best measured, 80.33 us) + T5 setprio around MFMA clusters.
// LDS 80 KiB: X f32 dbuf @0 (2x16K, aliases act) | W1/W2 triple-buffer @32K (3x16K)
__global__ __launch_bounds__(512, 4)
void fused_kernel(const float* __restrict__ X, char* __restrict__ ws,
                  float* __restrict__ out) {
  __shared__ char lds[81920];
  const int tid = threadIdx.x;
  const int lane = tid & 63, lr = lane & 15, lq = lane >> 4;
  const int wave = tid >> 6;
  const int wm1 = wave >> 1, wn1 = wave & 1;   // phase 1: 4m x 2n
  const int wm = wave >> 2, wn = wave & 3;     // phase 2: 2m x 4n

  const int raw = blockIdx.x;
  const int m = (raw & 7) * 64 + (raw >> 3);   // XCD-chunked, 512 % 8 == 0
  const int row0 = m << 6;
  const int b = m >> 6;

  const float* coef = (const float*)ws;
  const char* w1 = ws + W1_BYTE;
  const char* w2 = ws + W2_BYTE;

  // ===== phase 1: X @ Wd, 32 sub-steps of K=32, 1 barrier each =====
  const int srow = tid >> 4, sg = tid & 15;
  const float* xsrc = X + (size_t)(row0 + srow) * 1024 + ((sg ^ (srow & 15)) << 2);

  int aoff1[2][2];
#pragma unroll
  for (int h = 0; h < 2; ++h) {
    int r = wm1 * 16 + lr;
    int g0 = h * 8 + lq * 2;
    aoff1[h][0] = r * 256 + ((g0 ^ (r & 15)) << 4);
    aoff1[h][1] = r * 256 + (((g0 + 1) ^ (r & 15)) << 4);
  }
  int boff[8];
#pragma unroll
  for (int nf = 0; nf < 8; ++nf) {
    int n = wn1 * 128 + nf * 16 + lr;
    boff[nf] = n * 64 + ((lq ^ ((n >> 1) & 3)) << 4);
  }

  f32x4 acc1[8] = {};
  float hacc = 0.f;

  // X buffer t: [64 r][64 k] f32 at lds + (t&1)*16384 (aliases act region)
#define STAGE_X(t)                                                               \
  { char* xb = lds + ((t) & 1) * 16384;                                          \
    gl_lds16(xsrc + (size_t)(t) * 64, xb + tid * 16);                            \
    gl_lds16(xsrc + 32 * 1024 + (size_t)(t) * 64, xb + 8192 + tid * 16); }
  // W1 slice ks -> buffer ks%3 at lds + 32768 + (ks%3)*16384
#define STAGE_W1(ks)                                                             \
  { char* dst = lds + 32768 + ((ks) % 3) * 16384;                                \
    gl_lds16(w1 + (size_t)(ks) * 16384 + tid * 16, dst + tid * 16);              \
    gl_lds16(w1 + (size_t)(ks) * 16384 + 8192 + tid * 16, dst + 8192 + tid * 16); }

  // prologue: W1(0), X(0), W1(1) in flight; retire W1(0)+X(0)
  STAGE_W1(0); STAGE_X(0); STAGE_W1(1);
  VMW(2); BAR();

#pragma unroll
  for (int s = 0; s < 32; ++s) {
    // ---- issue stage (before compute) ----
    if (s + 2 < 32) STAGE_W1(s + 2);
    if ((s & 1) == 0 && (s >> 1) + 1 < 16) STAGE_X((s >> 1) + 1);
    // ---- compute sub-step: X buf (s>>1)&1, half s&1; W1 buf s%3 ----
    {
      const char* Xc = lds + ((s >> 1) & 1) * 16384;
      const char* Wb = lds + 32768 + (s % 3) * 16384;
      const int h = s & 1;
      f32x4 fa0 = *(const f32x4*)(Xc + aoff1[h][0]);
      f32x4 fa1 = *(const f32x4*)(Xc + aoff1[h][1]);
      if (wn1 == 0)
        hacc += fa0[0] + fa0[1] + fa0[2] + fa0[3] +
                fa1[0] + fa1[1] + fa1[2] + fa1[3];
      union { u32x4 u; s16x8 s_; } cv;
      cv.u[0] = cvt_pk(fa0[0], fa0[1]); cv.u[1] = cvt_pk(fa0[2], fa0[3]);
      cv.u[2] = cvt_pk(fa1[0], fa1[1]); cv.u[3] = cvt_pk(fa1[2], fa1[3]);
      s16x8 afr = cv.s_;
      s16x8 bfr[8];
#pragma unroll
      for (int nf = 0; nf < 8; ++nf) bfr[nf] = *(const s16x8*)(Wb + boff[nf]);
      PRIO_HI();
#pragma unroll
      for (int nf = 0; nf < 8; ++nf)
        acc1[nf] = __builtin_amdgcn_mfma_f32_16x16x32_bf16(afr, bfr[nf],
                                                           acc1[nf], 0, 0, 0);
      PRIO_LO();
    }
    LGKM0(); SB();
    // ---- counted trailing wait ----
    if (s == 30)            { VMW(0); }   // retire W1(31); nothing else in flight
    else if (s == 31)       { }           // all retired at s==30
    else if (s & 1)         { VMW(2); }   // retire W1(s+1)+X((s+1)/2); leave W1(s+2)
    else                    { VMW(4); }   // retire W1(s+1); leave W1(s+2)+X(t+1)
    BAR();
  }

  // ===== phase-1 epilogue: hsum, modulate+relu -> act LDS, asum =====
  float* hsumb = (float*)(lds + 32768);          // 64 f32 (W1 region dead)
  float* asp   = (float*)(lds + 33024);          // [2 wn1][64 r] f32
  if (wn1 == 0) {
    float s = hacc;
    s += __shfl_xor(s, 16); s += __shfl_xor(s, 32);
    if (lq == 0) hsumb[wm1 * 16 + lr] = s;
  }
  __syncthreads();

  float dgv[8], dbv[8];
#pragma unroll
  for (int nf = 0; nf < 8; ++nf) {
    int h = wn1 * 128 + nf * 16 + lr;
    dgv[nf] = coef[DG_OFF + b * 256 + h];
    dbv[nf] = coef[DB_OFF + b * 256 + h];
  }

  float asacc[4] = {};
#pragma unroll
  for (int nf = 0; nf < 8; ++nf) {
    int hh = wn1 * 128 + nf * 16 + lr;
    int kc = hh >> 6, kl = hh & 63;
    int g = kl >> 3;
    char* nbase = lds + kc * 8192 + (kl & 7) * 2;
    float dg_ = dgv[nf], db_ = dbv[nf];
#pragma unroll
    for (int j = 0; j < 4; ++j) {
      int r = wm1 * 16 + lq * 4 + j;
      float v = acc1[nf][j] * dg_ + db_ * hsumb[r];
      v = fmaxf(v, 0.f);
      asacc[j] += v;
      *(unsigned short*)(nbase + r * 128 + ((g ^ (r & 7)) << 4)) = f2bf(v);
    }
  }
#pragma unroll
  for (int j = 0; j < 4; ++j) {
    float s = asacc[j];
    s += __shfl_xor(s, 1); s += __shfl_xor(s, 2); s += __shfl_xor(s, 4); s += __shfl_xor(s, 8);
    if (lr == 0) asp[wn1 * 64 + wm1 * 16 + lq * 4 + j] = s;
  }
  __syncthreads();

  float asv[2][4];
#pragma unroll
  for (int mf = 0; mf < 2; ++mf)
#pragma unroll
    for (int j = 0; j < 4; ++j) {
      int r = wm * 32 + mf * 16 + lq * 4 + j;
      asv[mf][j] = asp[r] + asp[64 + r];
    }
  // preload all per-nt phase-2 modulation coefs (no in-loop coef loads)
  float ugA[8], ubA[8];
#pragma unroll
  for (int nt = 0; nt < 8; ++nt) {
    int d = nt * 128 + wn * 32 + lr;
    ugA[nt] = coef[UG_OFF + b * 1024 + d];
    ubA[nt] = coef[UB_OFF + b * 1024 + d];
  }
  float ugB[8], ubB[8];
#pragma unroll
  for (int nt = 0; nt < 8; ++nt) {
    int d = nt * 128 + wn * 32 + 16 + lr;
    ugB[nt] = coef[UG_OFF + b * 1024 + d];
    ubB[nt] = coef[UB_OFF + b * 1024 + d];
  }
  __syncthreads();   // asp consumed before W2 staging overwrites 32768..

  // ===== phase 2: act @ Wu, 32 steps (8 nt x 4 kc) — r15 sync + setprio =====
  int a2off[2][2], b2off[2][2];
#pragma unroll
  for (int mf = 0; mf < 2; ++mf)
#pragma unroll
    for (int kf = 0; kf < 2; ++kf) {
      int r = wm * 32 + mf * 16 + lr;
      a2off[mf][kf] = r * 128 + (((kf * 4 + lq) ^ (r & 7)) << 4);
    }
#pragma unroll
  for (int nf = 0; nf < 2; ++nf)
#pragma unroll
    for (int kf = 0; kf < 2; ++kf) {
      int nl = wn * 32 + nf * 16 + lr;
      b2off[nf][kf] = nl * 128 + (((kf * 4 + lq) ^ (nl & 7)) << 4);
    }

#define W2B(s) (lds + 32768 + ((s) % 3) * 16384)
#define STAGE_W2(s)                                                              \
  { gl_lds16(w2 + (size_t)(s) * 16384 + tid * 16, W2B(s) + tid * 16);            \
    gl_lds16(w2 + (size_t)(s) * 16384 + 8192 + tid * 16,                         \
             W2B(s) + 8192 + tid * 16); }

  STAGE_W2(0); STAGE_W2(1);
  VMW(2); BAR();

#pragma unroll
  for (int s = 0; s < 32; ++s) {
    const int nt = s >> 2, kc = s & 3;
    f32x4 acc2[2][2];
    if (kc == 0) {
#pragma unroll
      for (int mf = 0; mf < 2; ++mf)
#pragma unroll
        for (int nf = 0; nf < 2; ++nf) acc2[mf][nf] = (f32x4){0.f, 0.f, 0.f, 0.f};
    }
    const char* Wb = W2B(s);
#pragma unroll
    for (int kf = 0; kf < 2; ++kf) {
      s16x8 a2[2], bb[2];
#pragma unroll
      for (int mf = 0; mf < 2; ++mf)
        a2[mf] = *(const s16x8*)(lds + kc * 8192 + a2off[mf][kf]);
#pragma unroll
      for (int nf = 0; nf < 2; ++nf)
        bb[nf] = *(const s16x8*)(Wb + b2off[nf][kf]);
      PRIO_HI();
#pragma unroll
      for (int mf = 0; mf < 2; ++mf)
#pragma unroll
        for (int nf = 0; nf < 2; ++nf)
          acc2[mf][nf] = __builtin_amdgcn_mfma_f32_16x16x32_bf16(a2[mf], bb[nf], acc2[mf][nf], 0, 0, 0);
      PRIO_LO();
    }
    LGKM0(); SB();

    if (s + 2 < 32) STAGE_W2(s + 2);
    if (kc == 3) {
#pragma unroll
      for (int mf = 0; mf < 2; ++mf)
#pragma unroll
        for (int j = 0; j < 4; ++j) {
          int r = wm * 32 + mf * 16 + lq * 4 + j;
          size_t gbase = (size_t)(row0 + r) * 1024 + nt * 128 + wn * 32;
          size_t gi0 = gbase + lr;
          size_t gi1 = gbase + 16 + lr;
          out[gi0] = acc2[mf][0][j] * ugA[nt] + ubA[nt] * asv[mf][j] + X[gi0];
          out[gi1] = acc2[mf][1][j] * ugB[nt] + ubB[nt] * asv[mf][j] + X[gi1];
        }
    }
    if (s < 31) {
      if (s + 2 >= 32)  { VMW(0); }
      else if (kc == 3) { VMW(16); }
      else              { VMW(2); }
      BAR();
    }
  }
}

extern "C" void kernel_launch(void* const* d_in, const int* in_sizes, int n_in,
                              void* d_out, int out_size, void* d_ws, size_t ws_size,
                              hipStream_t stream) {
  const float* hidden       = (const float*)d_in[0];
  const float* conditions   = (const float*)d_in[1];
  const float* down_project = (const float*)d_in[2];
  const float* down_gamma   = (const float*)d_in[3];
  const float* down_beta    = (const float*)d_in[4];
  const float* up_project   = (const float*)d_in[5];
  const float* up_gamma     = (const float*)d_in[6];
  const float* up_beta      = (const float*)d_in[7];
  float* out = (float*)d_out;
  char* ws = (char*)d_ws;

  prep_kernel<<<224, 256, 0, stream>>>(conditions, down_gamma, down_beta, up_gamma, up_beta,
                                       down_project, up_project, ws);
  fused_kernel<<<512, 512, 0, stream>>>(hidden, ws, out);
}